// Round 13
// baseline (565.906 us; speedup 1.0000x reference)
//
#include <hip/hip_runtime.h>
#include <hip/hip_bf16.h>
#include <stdint.h>

typedef __bf16 bf16x8 __attribute__((ext_vector_type(8)));
typedef float  f32x4  __attribute__((ext_vector_type(4)));

#define H    128
#define KCH  8
#define NT   8
#define BM   64

// ---- ws byte layout ----
// meta ints: [0..8) cnt, [8..16) cur, [16..25) offs_padded, [25] stride, [26..34) end_valid
#define WS_TILET  2048      // ints: tile_type[ntiles] (<=3584)
#define WS_IDX    16384     // ints: idx[N + NT*(BM-1)]  (~402KB < 458752-16384)
#define WS_UF     458752    // bf16 image: 8 types * 32KB (swizzled for LDS)
#define WS_W      720896    // bf16: 8 types * 384*256 transposed (linear)

__device__ __forceinline__ float fsigm(float v){ return 1.f/(1.f+__expf(-v)); }
__device__ __forceinline__ float ftanh(float v){
  v = fminf(fmaxf(v,-15.f),15.f);
  float e = __expf(2.f*v);
  return (e-1.f)/(e+1.f);
}

__global__ void k_init(int* ws){ if (threadIdx.x < 40) ws[threadIdx.x] = 0; }

__global__ void k_detect(const int* __restrict__ type_id, int* ws){
  __shared__ int nz;
  if (threadIdx.x == 0) nz = 0;
  __syncthreads();
  int v = type_id[threadIdx.x];
  if ((threadIdx.x & 1) && v != 0) atomicAdd(&nz, 1);
  __syncthreads();
  if (threadIdx.x == 0) ws[25] = (nz == 0) ? 2 : 1;
}

__global__ void k_count(const int* __restrict__ type_id, int* __restrict__ ws, int N){
  __shared__ int h[NT];
  int tid = threadIdx.x;
  if (tid < NT) h[tid] = 0;
  __syncthreads();
  int stride = ws[25];
  int i = blockIdx.x*blockDim.x + tid;
  if (i < N) atomicAdd(&h[type_id[(size_t)i*stride]], 1);
  __syncthreads();
  if (tid < NT) atomicAdd(&ws[tid], h[tid]);
}

__global__ void k_scan(int* m){
  int s = 0;
  for (int t=0;t<NT;++t){
    m[16+t] = s;
    m[8+t]  = s;
    m[26+t] = s + m[t];
    s += ((m[t]+BM-1)/BM)*BM;
  }
  m[24] = s;
}

__global__ void k_scatter(const int* __restrict__ type_id, int* __restrict__ ws, int N){
  __shared__ int h[NT], base[NT];
  int tid = threadIdx.x;
  if (tid < NT) h[tid] = 0;
  __syncthreads();
  int stride = ws[25];
  int i = blockIdx.x*blockDim.x + tid;
  int t = 0, lp = 0;
  if (i < N){ t = type_id[(size_t)i*stride]; lp = atomicAdd(&h[t], 1); }
  __syncthreads();
  if (tid < NT) base[tid] = atomicAdd(&ws[8+tid], h[tid]);
  __syncthreads();
  if (i < N) ws[(WS_IDX/4) + base[t] + lp] = i;
}

__global__ void k_tiletype(int* ws, int ntiles){
  int i = blockIdx.x*256 + threadIdx.x;
  if (i >= ntiles) return;
  const int* op = ws + 16;
  int p = i*BM, t = -1;
  if (p < op[8]){
    for (int s=0;s<NT;++s) if (p >= op[s] && p < op[s+1]) t = s;
  }
  ws[(WS_TILET/4) + i] = t;
}

// UfT swizzled image: dst 16B slot gid=(t*128+c)*16+sp holds U_f[t][8*(sp^(c&7))+j][c]
__global__ void k_prep_uf(const float* __restrict__ U_f, char* __restrict__ ws){
  int gid = blockIdx.x*256 + threadIdx.x;
  if (gid >= NT*128*16) return;
  int sp = gid & 15, c = (gid>>4) & 127, t = gid >> 11;
  int kbase = 8*(sp ^ (c & 7));
  const float* src = U_f + ((size_t)t*H + kbase)*H + c;
  bf16x8 v;
  #pragma unroll
  for (int j=0;j<8;++j) v[j] = (__bf16)src[(size_t)j*H];
  *(bf16x8*)(ws + WS_UF + (size_t)gid*16) = v;
}

// WcatT linear: (t,col,K0) at WS_W + ((t*384+col)*256+K0)*2 ; Wcat = [W_iou ; U_iou]
__global__ void k_prep_w(const float* __restrict__ W_iou, const float* __restrict__ U_iou,
                         char* __restrict__ ws){
  int gid = blockIdx.x*256 + threadIdx.x;
  if (gid >= NT*384*32) return;
  int sp = gid & 31, col = (gid>>5) % 384, t = gid / (384*32);
  int K0 = sp*8;
  bf16x8 v;
  #pragma unroll
  for (int j=0;j<8;++j){
    int K = K0 + j;
    float f = (K < H) ? W_iou[((size_t)t*H + K)*(3*H) + col]
                      : U_iou[((size_t)t*H + (K-H))*(3*H) + col];
    v[j] = (__bf16)f;
  }
  *(bf16x8*)(ws + WS_W + (size_t)gid*16) = v;
}

// ============ FUSED kernel, BM=64, 512 threads, LDS 64KB -> 2 blocks/CU ============
// LDS: uf [0,32768) rows 256B ; nh0 [32768,49152) ; nh1 [49152,65536) (64 rows x 256B each)
// act phase reuses [32768,65536) as 64 rows x 512B.
// D' = [outcol][node]; spill guards: unroll 1 child loop, st-outer phase A.
__global__ __launch_bounds__(512,4) void k_fused(
  const float* __restrict__ x, const float* __restrict__ n_h, const float* __restrict__ n_c,
  const float* __restrict__ b_iou, const float* __restrict__ b_f,
  const char* __restrict__ ws, float* __restrict__ out, int N)
{
  __shared__ __align__(16) char lds[65536];
  const int* meta = (const int*)ws;
  int tile = blockIdx.x;
  int t = ((const int*)(ws + WS_TILET))[tile];
  if (t < 0) return;
  int ev = meta[26 + t];
  const int* idx = (const int*)(ws + WS_IDX);

  int tid = threadIdx.x;
  int lane = tid & 63, wave = tid >> 6;
  int rw = wave & 3, cw = wave >> 2;      // rw: node quarter (4x16=64), cw: outcol half
  int l15 = lane & 15, l4 = lane >> 4;
  int base = tile*BM;

  // staging role: 8 threads per node row (64 rows)
  int mrow = tid >> 3, mcol = (tid & 7) * 16;
  int mpos = base + mrow;
  int mnode = (mpos < ev) ? idx[mpos] : 0;

  // gate role: one node per lane, 4 outcol quads
  int npos = base + rw*16 + l15;
  bool valn = npos < ev;
  int nd = valn ? idx[npos] : 0;
  const float* ncb = n_c + (size_t)nd*(KCH*H);
  int ocb[4]; f32x4 bf4[4];
  #pragma unroll
  for (int st=0; st<4; ++st){
    ocb[st] = cw*64 + st*16 + 4*l4;
    bf4[st] = *(const f32x4*)(b_f + t*H + ocb[st]);
  }

  // stage UfT image -> LDS (512 threads: 4 x 8KB)
  {
    const char* src = ws + WS_UF + (size_t)t*32768;
    #pragma unroll
    for (int it=0; it<4; ++it){
      bf16x8 v = *(const bf16x8*)(src + it*8192 + tid*16);
      *(bf16x8*)(lds + it*8192 + tid*16) = v;
    }
  }

  const float* nh_base = n_h + (size_t)mnode*(KCH*H) + mcol;

  float hsum[16];
  #pragma unroll
  for (int j=0;j<16;++j) hsum[j] = 0.f;
  f32x4 cacc[4];
  #pragma unroll
  for (int st=0;st<4;++st) cacc[st] = (f32x4){0.f,0.f,0.f,0.f};

  int arow = rw*16 + l15;
  int aswz = (arow & 7) << 4;
  int mswz = (mrow & 7) << 4;

  // prologue: stage child 0 -> buf0 + prefetch nc for k=0 (shares the UF barrier)
  f32x4 nc_cur[4];
  #pragma unroll
  for (int st=0;st<4;++st) nc_cur[st] = *(const f32x4*)(ncb + ocb[st]);
  {
    const float4* p = (const float4*)nh_base;
    float4 a0=p[0], a1=p[1], a2=p[2], a3=p[3];
    hsum[0]+=a0.x;  hsum[1]+=a0.y;  hsum[2]+=a0.z;  hsum[3]+=a0.w;
    hsum[4]+=a1.x;  hsum[5]+=a1.y;  hsum[6]+=a1.z;  hsum[7]+=a1.w;
    hsum[8]+=a2.x;  hsum[9]+=a2.y;  hsum[10]+=a2.z; hsum[11]+=a2.w;
    hsum[12]+=a3.x; hsum[13]+=a3.y; hsum[14]+=a3.z; hsum[15]+=a3.w;
    bf16x8 w0, w1;
    w0[0]=(__bf16)a0.x; w0[1]=(__bf16)a0.y; w0[2]=(__bf16)a0.z; w0[3]=(__bf16)a0.w;
    w0[4]=(__bf16)a1.x; w0[5]=(__bf16)a1.y; w0[6]=(__bf16)a1.z; w0[7]=(__bf16)a1.w;
    w1[0]=(__bf16)a2.x; w1[1]=(__bf16)a2.y; w1[2]=(__bf16)a2.z; w1[3]=(__bf16)a2.w;
    w1[4]=(__bf16)a3.x; w1[5]=(__bf16)a3.y; w1[6]=(__bf16)a3.z; w1[7]=(__bf16)a3.w;
    *(bf16x8*)(lds + 32768 + mrow*256 + (( mcol*2      ) ^ mswz)) = w0;
    *(bf16x8*)(lds + 32768 + mrow*256 + (( mcol*2 + 16 ) ^ mswz)) = w1;
  }
  __syncthreads();

  // child loop: dbuf, 1 barrier/iter; nh & n_c both prefetched one iter ahead
  #pragma unroll 1
  for (int k=0;k<KCH;++k){
    const int cur = 32768 + (k&1)*16384;
    const int nxt = 32768 + ((k+1)&1)*16384;
    float4 b0,b1,b2,b3;
    f32x4 nc_nxt[4];
    if (k < KCH-1){
      const float4* p = (const float4*)(nh_base + (size_t)(k+1)*H);
      b0=p[0]; b1=p[1]; b2=p[2]; b3=p[3];
      #pragma unroll
      for (int st=0;st<4;++st) nc_nxt[st] = *(const f32x4*)(ncb + (size_t)(k+1)*H + ocb[st]);
    }

    f32x4 fa[4];
    #pragma unroll
    for (int st=0;st<4;++st) fa[st] = (f32x4){0.f,0.f,0.f,0.f};
    #pragma unroll
    for (int kk=0; kk<4; ++kk){
      int kb = kk*64 + l4*16;
      bf16x8 bnh = *(const bf16x8*)(lds + cur + arow*256 + (kb ^ aswz));
      #pragma unroll
      for (int st=0;st<4;++st){
        int c = cw*64 + st*16 + l15;
        bf16x8 auf = *(const bf16x8*)(lds + c*256 + (kb ^ ((c&7)<<4)));
        fa[st] = __builtin_amdgcn_mfma_f32_16x16x32_bf16(auf, bnh, fa[st], 0,0,0);
      }
    }
    #pragma unroll
    for (int st=0;st<4;++st){
      #pragma unroll
      for (int r=0;r<4;++r){
        float fg = fsigm(fa[st][r] + bf4[st][r]);
        cacc[st][r] += fg * nc_cur[st][r];
      }
    }

    if (k < KCH-1){
      hsum[0]+=b0.x;  hsum[1]+=b0.y;  hsum[2]+=b0.z;  hsum[3]+=b0.w;
      hsum[4]+=b1.x;  hsum[5]+=b1.y;  hsum[6]+=b1.z;  hsum[7]+=b1.w;
      hsum[8]+=b2.x;  hsum[9]+=b2.y;  hsum[10]+=b2.z; hsum[11]+=b2.w;
      hsum[12]+=b3.x; hsum[13]+=b3.y; hsum[14]+=b3.z; hsum[15]+=b3.w;
      bf16x8 w0, w1;
      w0[0]=(__bf16)b0.x; w0[1]=(__bf16)b0.y; w0[2]=(__bf16)b0.z; w0[3]=(__bf16)b0.w;
      w0[4]=(__bf16)b1.x; w0[5]=(__bf16)b1.y; w0[6]=(__bf16)b1.z; w0[7]=(__bf16)b1.w;
      w1[0]=(__bf16)b2.x; w1[1]=(__bf16)b2.y; w1[2]=(__bf16)b2.z; w1[3]=(__bf16)b2.w;
      w1[4]=(__bf16)b3.x; w1[5]=(__bf16)b3.y; w1[6]=(__bf16)b3.z; w1[7]=(__bf16)b3.w;
      *(bf16x8*)(lds + nxt + mrow*256 + (( mcol*2      ) ^ mswz)) = w0;
      *(bf16x8*)(lds + nxt + mrow*256 + (( mcol*2 + 16 ) ^ mswz)) = w1;
      #pragma unroll
      for (int st=0;st<4;++st) nc_cur[st] = nc_nxt[st];
    }
    __syncthreads();
  }

  // ---- act = [x | h_sum] bf16 into [32768, 65536), 64 rows x 512B ----
  {
    const float4* px = (const float4*)(x + (size_t)mnode*H + mcol);
    float4 x0=px[0], x1=px[1], x2=px[2], x3=px[3];
    bf16x8 w0,w1,w2,w3;
    w0[0]=(__bf16)x0.x; w0[1]=(__bf16)x0.y; w0[2]=(__bf16)x0.z; w0[3]=(__bf16)x0.w;
    w0[4]=(__bf16)x1.x; w0[5]=(__bf16)x1.y; w0[6]=(__bf16)x1.z; w0[7]=(__bf16)x1.w;
    w1[0]=(__bf16)x2.x; w1[1]=(__bf16)x2.y; w1[2]=(__bf16)x2.z; w1[3]=(__bf16)x2.w;
    w1[4]=(__bf16)x3.x; w1[5]=(__bf16)x3.y; w1[6]=(__bf16)x3.z; w1[7]=(__bf16)x3.w;
    #pragma unroll
    for (int j=0;j<8;++j){ w2[j]=(__bf16)hsum[j]; w3[j]=(__bf16)hsum[8+j]; }
    int ab = 32768 + mrow*512;
    *(bf16x8*)(lds + ab + (( mcol*2            ) ^ mswz)) = w0;
    *(bf16x8*)(lds + ab + (( mcol*2 + 16       ) ^ mswz)) = w1;
    *(bf16x8*)(lds + ab + (( 256 + mcol*2      ) ^ mswz)) = w2;
    *(bf16x8*)(lds + ab + (( 256 + mcol*2 + 16 ) ^ mswz)) = w3;
  }
  __syncthreads();

  // ---- phase A: iou = act @ WcatT (W direct from L2), st-outer, c_aggr from regs ----
  const char* wbase = ws + WS_W + (size_t)t*(384*256*2);
  #pragma unroll
  for (int st=0; st<4; ++st){
    f32x4 ag[3];
    #pragma unroll
    for (int g=0;g<3;++g) ag[g] = (f32x4){0.f,0.f,0.f,0.f};
    const char* wrow = wbase + (size_t)(cw*64 + st*16 + l15)*512;
    #pragma unroll 2
    for (int kc=0;kc<4;++kc){
      #pragma unroll
      for (int kk2=0;kk2<2;++kk2){
        int kb = kc*128 + kk2*64 + l4*16;
        bf16x8 bact = *(const bf16x8*)(lds + 32768 + arow*512 + (kb ^ aswz));
        #pragma unroll
        for (int g=0;g<3;++g){
          bf16x8 aW = *(const bf16x8*)(wrow + (size_t)(g*128)*512 + kb);
          ag[g] = __builtin_amdgcn_mfma_f32_16x16x32_bf16(aW, bact, ag[g], 0,0,0);
        }
      }
    }
    if (valn){
      f32x4 bi4 = *(const f32x4*)(b_iou + t*(3*H) +        ocb[st]);
      f32x4 bo4 = *(const f32x4*)(b_iou + t*(3*H) + H   +  ocb[st]);
      f32x4 bu4 = *(const f32x4*)(b_iou + t*(3*H) + 2*H +  ocb[st]);
      f32x4 hv4, cv4;
      #pragma unroll
      for (int r=0;r<4;++r){
        float ig = ag[0][r] + bi4[r];
        float og = ag[1][r] + bo4[r];
        float ug = ag[2][r] + bu4[r];
        float cv = fsigm(ig)*ftanh(ug) + cacc[st][r];
        float hv = fsigm(og)*ftanh(cv);
        cv4[r] = cv; hv4[r] = hv;
      }
      *(f32x4*)(out + (size_t)nd*H + ocb[st]) = hv4;
      *(f32x4*)(out + (size_t)N*H + (size_t)nd*H + ocb[st]) = cv4;
    }
  }
}

extern "C" void kernel_launch(void* const* d_in, const int* in_sizes, int n_in,
                              void* d_out, int out_size, void* d_ws, size_t ws_size,
                              hipStream_t stream){
  const float* x      = (const float*)d_in[0];
  const float* n_h    = (const float*)d_in[1];
  const float* n_c    = (const float*)d_in[2];
  const int*   typ    = (const int*)d_in[3];
  const float* W_iou  = (const float*)d_in[4];
  const float* U_iou  = (const float*)d_in[5];
  const float* b_iou  = (const float*)d_in[6];
  const float* U_f    = (const float*)d_in[7];
  const float* b_f    = (const float*)d_in[8];
  float* out = (float*)d_out;
  int*   ws  = (int*)d_ws;
  char*  wsc = (char*)d_ws;
  int N = in_sizes[0] / H;
  int nb = (N + 255) / 256;
  int ntiles = (N + NT*(BM-1) + BM-1) / BM;

  hipLaunchKernelGGL(k_init,     dim3(1),   dim3(64),  0, stream, ws);
  hipLaunchKernelGGL(k_detect,   dim3(1),   dim3(256), 0, stream, typ, ws);
  hipLaunchKernelGGL(k_count,    dim3(nb),  dim3(256), 0, stream, typ, ws, N);
  hipLaunchKernelGGL(k_scan,     dim3(1),   dim3(1),   0, stream, ws);
  hipLaunchKernelGGL(k_scatter,  dim3(nb),  dim3(256), 0, stream, typ, ws, N);
  hipLaunchKernelGGL(k_tiletype, dim3((ntiles+255)/256), dim3(256), 0, stream, ws, ntiles);
  hipLaunchKernelGGL(k_prep_uf,  dim3((NT*128*16+255)/256), dim3(256), 0, stream, U_f, wsc);
  hipLaunchKernelGGL(k_prep_w,   dim3((NT*384*32+255)/256), dim3(256), 0, stream, W_iou, U_iou, wsc);
  hipLaunchKernelGGL(k_fused,    dim3(ntiles), dim3(512), 0, stream,
                     x, n_h, n_c, b_iou, b_f, wsc, out, N);
}

// Round 14
// 347.148 us; speedup vs baseline: 1.6302x; 1.6302x over previous
//
#include <hip/hip_runtime.h>
#include <hip/hip_bf16.h>
#include <stdint.h>

typedef __bf16 bf16x8 __attribute__((ext_vector_type(8)));
typedef float  f32x4  __attribute__((ext_vector_type(4)));

#define H    128
#define KCH  8
#define NT   8
#define BM   32

// ---- ws byte layout ----
// meta ints: [0..8) cnt, [8..16) cur, [16..25) offs_padded, [25] stride, [26..34) end_valid
#define WS_TILET  2048      // ints: tile_type[ntiles]
#define WS_IDX    16384     // ints: idx[N + NT*(BM-1)]
#define WS_UF     458752    // bf16 image: 8 types * 32KB (swizzled for LDS)
#define WS_W      720896    // bf16: 8 types * 384*256 transposed (linear)

__device__ __forceinline__ float fsigm(float v){ return 1.f/(1.f+__expf(-v)); }
__device__ __forceinline__ float ftanh(float v){
  v = fminf(fmaxf(v,-15.f),15.f);
  float e = __expf(2.f*v);
  return (e-1.f)/(e+1.f);
}

__global__ void k_init(int* ws){ if (threadIdx.x < 40) ws[threadIdx.x] = 0; }

__global__ void k_detect(const int* __restrict__ type_id, int* ws){
  __shared__ int nz;
  if (threadIdx.x == 0) nz = 0;
  __syncthreads();
  int v = type_id[threadIdx.x];
  if ((threadIdx.x & 1) && v != 0) atomicAdd(&nz, 1);
  __syncthreads();
  if (threadIdx.x == 0) ws[25] = (nz == 0) ? 2 : 1;
}

__global__ void k_count(const int* __restrict__ type_id, int* __restrict__ ws, int N){
  __shared__ int h[NT];
  int tid = threadIdx.x;
  if (tid < NT) h[tid] = 0;
  __syncthreads();
  int stride = ws[25];
  int i = blockIdx.x*blockDim.x + tid;
  if (i < N) atomicAdd(&h[type_id[(size_t)i*stride]], 1);
  __syncthreads();
  if (tid < NT) atomicAdd(&ws[tid], h[tid]);
}

__global__ void k_scan(int* m){
  int s = 0;
  for (int t=0;t<NT;++t){
    m[16+t] = s;
    m[8+t]  = s;
    m[26+t] = s + m[t];
    s += ((m[t]+BM-1)/BM)*BM;
  }
  m[24] = s;
}

__global__ void k_scatter(const int* __restrict__ type_id, int* __restrict__ ws, int N){
  __shared__ int h[NT], base[NT];
  int tid = threadIdx.x;
  if (tid < NT) h[tid] = 0;
  __syncthreads();
  int stride = ws[25];
  int i = blockIdx.x*blockDim.x + tid;
  int t = 0, lp = 0;
  if (i < N){ t = type_id[(size_t)i*stride]; lp = atomicAdd(&h[t], 1); }
  __syncthreads();
  if (tid < NT) base[tid] = atomicAdd(&ws[8+tid], h[tid]);
  __syncthreads();
  if (i < N) ws[(WS_IDX/4) + base[t] + lp] = i;
}

__global__ void k_tiletype(int* ws, int ntiles){
  int i = blockIdx.x*256 + threadIdx.x;
  if (i >= ntiles) return;
  const int* op = ws + 16;
  int p = i*BM, t = -1;
  if (p < op[8]){
    for (int s=0;s<NT;++s) if (p >= op[s] && p < op[s+1]) t = s;
  }
  ws[(WS_TILET/4) + i] = t;
}

// UfT swizzled image: dst 16B slot gid=(t*128+c)*16+sp holds U_f[t][8*(sp^(c&7))+j][c]
__global__ void k_prep_uf(const float* __restrict__ U_f, char* __restrict__ ws){
  int gid = blockIdx.x*256 + threadIdx.x;
  if (gid >= NT*128*16) return;
  int sp = gid & 15, c = (gid>>4) & 127, t = gid >> 11;
  int kbase = 8*(sp ^ (c & 7));
  const float* src = U_f + ((size_t)t*H + kbase)*H + c;
  bf16x8 v;
  #pragma unroll
  for (int j=0;j<8;++j) v[j] = (__bf16)src[(size_t)j*H];
  *(bf16x8*)(ws + WS_UF + (size_t)gid*16) = v;
}

// WcatT linear: (t,col,K0) at WS_W + ((t*384+col)*256+K0)*2 ; Wcat = [W_iou ; U_iou]
__global__ void k_prep_w(const float* __restrict__ W_iou, const float* __restrict__ U_iou,
                         char* __restrict__ ws){
  int gid = blockIdx.x*256 + threadIdx.x;
  if (gid >= NT*384*32) return;
  int sp = gid & 31, col = (gid>>5) % 384, t = gid / (384*32);
  int K0 = sp*8;
  bf16x8 v;
  #pragma unroll
  for (int j=0;j<8;++j){
    int K = K0 + j;
    float f = (K < H) ? W_iou[((size_t)t*H + K)*(3*H) + col]
                      : U_iou[((size_t)t*H + (K-H))*(3*H) + col];
    v[j] = (__bf16)f;
  }
  *(bf16x8*)(ws + WS_W + (size_t)gid*16) = v;
}

// ============ FUSED kernel: child aggregation + iou GEMM + gates ============
// LDS 48KB: uf [0,32768) ; nh0 [32768,40960) ; nh1 [40960,49152)
// act phase reuses [32768,49152) as 32 rows x 512B.
// D' = [outcol][node]; spill guards: unroll 1 child loop, st-outer phase A.
// R14: nc issued first, gate moved after barrier, setprio around MFMA cluster.
__global__ __launch_bounds__(256,3) void k_fused(
  const float* __restrict__ x, const float* __restrict__ n_h, const float* __restrict__ n_c,
  const float* __restrict__ b_iou, const float* __restrict__ b_f,
  const char* __restrict__ ws, float* __restrict__ out, int N)
{
  __shared__ __align__(16) char lds[49152];
  const int* meta = (const int*)ws;
  int tile = blockIdx.x;
  int t = ((const int*)(ws + WS_TILET))[tile];
  if (t < 0) return;
  int ev = meta[26 + t];
  const int* idx = (const int*)(ws + WS_IDX);

  int tid = threadIdx.x;
  int lane = tid & 63, wave = tid >> 6;
  int rw = wave & 1, cw = wave >> 1;
  int l15 = lane & 15, l4 = lane >> 4;
  int base = tile*BM;

  // staging role: 8 threads per node row
  int mrow = tid >> 3, mcol = (tid & 7) * 16;
  int mpos = base + mrow;
  int mnode = (mpos < ev) ? idx[mpos] : 0;

  // gate role: one node per lane, 4 outcol quads
  int npos = base + rw*16 + l15;
  bool valn = npos < ev;
  int nd = valn ? idx[npos] : 0;
  const float* ncb = n_c + (size_t)nd*(KCH*H);
  int ocb[4]; f32x4 bf4[4];
  #pragma unroll
  for (int st=0; st<4; ++st){
    ocb[st] = cw*64 + st*16 + 4*l4;
    bf4[st] = *(const f32x4*)(b_f + t*H + ocb[st]);
  }

  // stage UfT image -> LDS
  {
    const char* src = ws + WS_UF + (size_t)t*32768;
    #pragma unroll
    for (int it=0; it<8; ++it){
      bf16x8 v = *(const bf16x8*)(src + it*4096 + tid*16);
      *(bf16x8*)(lds + it*4096 + tid*16) = v;
    }
  }

  const float* nh_base = n_h + (size_t)mnode*(KCH*H) + mcol;

  float hsum[16];
  #pragma unroll
  for (int j=0;j<16;++j) hsum[j] = 0.f;
  f32x4 cacc[4];
  #pragma unroll
  for (int st=0;st<4;++st) cacc[st] = (f32x4){0.f,0.f,0.f,0.f};

  int arow = rw*16 + l15;
  int aswz = (arow & 7) << 4;
  int mswz = (mrow & 7) << 4;

  // prologue: stage child 0 -> buf0 (shares the UF barrier)
  {
    const float4* p = (const float4*)nh_base;
    float4 a0=p[0], a1=p[1], a2=p[2], a3=p[3];
    hsum[0]+=a0.x;  hsum[1]+=a0.y;  hsum[2]+=a0.z;  hsum[3]+=a0.w;
    hsum[4]+=a1.x;  hsum[5]+=a1.y;  hsum[6]+=a1.z;  hsum[7]+=a1.w;
    hsum[8]+=a2.x;  hsum[9]+=a2.y;  hsum[10]+=a2.z; hsum[11]+=a2.w;
    hsum[12]+=a3.x; hsum[13]+=a3.y; hsum[14]+=a3.z; hsum[15]+=a3.w;
    bf16x8 w0, w1;
    w0[0]=(__bf16)a0.x; w0[1]=(__bf16)a0.y; w0[2]=(__bf16)a0.z; w0[3]=(__bf16)a0.w;
    w0[4]=(__bf16)a1.x; w0[5]=(__bf16)a1.y; w0[6]=(__bf16)a1.z; w0[7]=(__bf16)a1.w;
    w1[0]=(__bf16)a2.x; w1[1]=(__bf16)a2.y; w1[2]=(__bf16)a2.z; w1[3]=(__bf16)a2.w;
    w1[4]=(__bf16)a3.x; w1[5]=(__bf16)a3.y; w1[6]=(__bf16)a3.z; w1[7]=(__bf16)a3.w;
    *(bf16x8*)(lds + 32768 + mrow*256 + (( mcol*2      ) ^ mswz)) = w0;
    *(bf16x8*)(lds + 32768 + mrow*256 + (( mcol*2 + 16 ) ^ mswz)) = w1;
  }
  __syncthreads();

  // child loop: dbuf, 1 barrier/iter; nc first, gate after barrier
  #pragma unroll 1
  for (int k=0;k<KCH;++k){
    const int cur = 32768 + (k&1)*8192;
    const int nxt = 32768 + ((k+1)&1)*8192;

    f32x4 nc4[4];
    #pragma unroll
    for (int st=0;st<4;++st) nc4[st] = *(const f32x4*)(ncb + (size_t)k*H + ocb[st]);

    float4 b0,b1,b2,b3;
    if (k < KCH-1){
      const float4* p = (const float4*)(nh_base + (size_t)(k+1)*H);
      b0=p[0]; b1=p[1]; b2=p[2]; b3=p[3];
    }

    f32x4 fa[4];
    #pragma unroll
    for (int st=0;st<4;++st) fa[st] = (f32x4){0.f,0.f,0.f,0.f};
    __builtin_amdgcn_s_setprio(1);
    #pragma unroll
    for (int kk=0; kk<4; ++kk){
      int kb = kk*64 + l4*16;
      bf16x8 bnh = *(const bf16x8*)(lds + cur + arow*256 + (kb ^ aswz));
      #pragma unroll
      for (int st=0;st<4;++st){
        int c = cw*64 + st*16 + l15;
        bf16x8 auf = *(const bf16x8*)(lds + c*256 + (kb ^ ((c&7)<<4)));
        fa[st] = __builtin_amdgcn_mfma_f32_16x16x32_bf16(auf, bnh, fa[st], 0,0,0);
      }
    }
    __builtin_amdgcn_s_setprio(0);

    if (k < KCH-1){
      hsum[0]+=b0.x;  hsum[1]+=b0.y;  hsum[2]+=b0.z;  hsum[3]+=b0.w;
      hsum[4]+=b1.x;  hsum[5]+=b1.y;  hsum[6]+=b1.z;  hsum[7]+=b1.w;
      hsum[8]+=b2.x;  hsum[9]+=b2.y;  hsum[10]+=b2.z; hsum[11]+=b2.w;
      hsum[12]+=b3.x; hsum[13]+=b3.y; hsum[14]+=b3.z; hsum[15]+=b3.w;
      bf16x8 w0, w1;
      w0[0]=(__bf16)b0.x; w0[1]=(__bf16)b0.y; w0[2]=(__bf16)b0.z; w0[3]=(__bf16)b0.w;
      w0[4]=(__bf16)b1.x; w0[5]=(__bf16)b1.y; w0[6]=(__bf16)b1.z; w0[7]=(__bf16)b1.w;
      w1[0]=(__bf16)b2.x; w1[1]=(__bf16)b2.y; w1[2]=(__bf16)b2.z; w1[3]=(__bf16)b2.w;
      w1[4]=(__bf16)b3.x; w1[5]=(__bf16)b3.y; w1[6]=(__bf16)b3.z; w1[7]=(__bf16)b3.w;
      *(bf16x8*)(lds + nxt + mrow*256 + (( mcol*2      ) ^ mswz)) = w0;
      *(bf16x8*)(lds + nxt + mrow*256 + (( mcol*2 + 16 ) ^ mswz)) = w1;
    }
    __syncthreads();

    // gate after barrier: nc latency folded into the barrier wait
    #pragma unroll
    for (int st=0;st<4;++st){
      #pragma unroll
      for (int r=0;r<4;++r){
        float fg = fsigm(fa[st][r] + bf4[st][r]);
        cacc[st][r] += fg * nc4[st][r];
      }
    }
  }

  // ---- act = [x | h_sum] bf16 into [32768, 49152), rows 512B ----
  {
    const float4* px = (const float4*)(x + (size_t)mnode*H + mcol);
    float4 x0=px[0], x1=px[1], x2=px[2], x3=px[3];
    bf16x8 w0,w1,w2,w3;
    w0[0]=(__bf16)x0.x; w0[1]=(__bf16)x0.y; w0[2]=(__bf16)x0.z; w0[3]=(__bf16)x0.w;
    w0[4]=(__bf16)x1.x; w0[5]=(__bf16)x1.y; w0[6]=(__bf16)x1.z; w0[7]=(__bf16)x1.w;
    w1[0]=(__bf16)x2.x; w1[1]=(__bf16)x2.y; w1[2]=(__bf16)x2.z; w1[3]=(__bf16)x2.w;
    w1[4]=(__bf16)x3.x; w1[5]=(__bf16)x3.y; w1[6]=(__bf16)x3.z; w1[7]=(__bf16)x3.w;
    #pragma unroll
    for (int j=0;j<8;++j){ w2[j]=(__bf16)hsum[j]; w3[j]=(__bf16)hsum[8+j]; }
    int ab = 32768 + mrow*512;
    *(bf16x8*)(lds + ab + (( mcol*2            ) ^ mswz)) = w0;
    *(bf16x8*)(lds + ab + (( mcol*2 + 16       ) ^ mswz)) = w1;
    *(bf16x8*)(lds + ab + (( 256 + mcol*2      ) ^ mswz)) = w2;
    *(bf16x8*)(lds + ab + (( 256 + mcol*2 + 16 ) ^ mswz)) = w3;
  }
  __syncthreads();

  // ---- phase A: iou = act @ WcatT (W direct from L2), st-outer, c_aggr from regs ----
  const char* wbase = ws + WS_W + (size_t)t*(384*256*2);
  #pragma unroll
  for (int st=0; st<4; ++st){
    f32x4 ag[3];
    #pragma unroll
    for (int g=0;g<3;++g) ag[g] = (f32x4){0.f,0.f,0.f,0.f};
    const char* wrow = wbase + (size_t)(cw*64 + st*16 + l15)*512;
    #pragma unroll 2
    for (int kc=0;kc<4;++kc){
      #pragma unroll
      for (int kk2=0;kk2<2;++kk2){
        int kb = kc*128 + kk2*64 + l4*16;
        bf16x8 bact = *(const bf16x8*)(lds + 32768 + arow*512 + (kb ^ aswz));
        #pragma unroll
        for (int g=0;g<3;++g){
          bf16x8 aW = *(const bf16x8*)(wrow + (size_t)(g*128)*512 + kb);
          ag[g] = __builtin_amdgcn_mfma_f32_16x16x32_bf16(aW, bact, ag[g], 0,0,0);
        }
      }
    }
    if (valn){
      f32x4 bi4 = *(const f32x4*)(b_iou + t*(3*H) +        ocb[st]);
      f32x4 bo4 = *(const f32x4*)(b_iou + t*(3*H) + H   +  ocb[st]);
      f32x4 bu4 = *(const f32x4*)(b_iou + t*(3*H) + 2*H +  ocb[st]);
      f32x4 hv4, cv4;
      #pragma unroll
      for (int r=0;r<4;++r){
        float ig = ag[0][r] + bi4[r];
        float og = ag[1][r] + bo4[r];
        float ug = ag[2][r] + bu4[r];
        float cv = fsigm(ig)*ftanh(ug) + cacc[st][r];
        float hv = fsigm(og)*ftanh(cv);
        cv4[r] = cv; hv4[r] = hv;
      }
      *(f32x4*)(out + (size_t)nd*H + ocb[st]) = hv4;
      *(f32x4*)(out + (size_t)N*H + (size_t)nd*H + ocb[st]) = cv4;
    }
  }
}

extern "C" void kernel_launch(void* const* d_in, const int* in_sizes, int n_in,
                              void* d_out, int out_size, void* d_ws, size_t ws_size,
                              hipStream_t stream){
  const float* x      = (const float*)d_in[0];
  const float* n_h    = (const float*)d_in[1];
  const float* n_c    = (const float*)d_in[2];
  const int*   typ    = (const int*)d_in[3];
  const float* W_iou  = (const float*)d_in[4];
  const float* U_iou  = (const float*)d_in[5];
  const float* b_iou  = (const float*)d_in[6];
  const float* U_f    = (const float*)d_in[7];
  const float* b_f    = (const float*)d_in[8];
  float* out = (float*)d_out;
  int*   ws  = (int*)d_ws;
  char*  wsc = (char*)d_ws;
  int N = in_sizes[0] / H;
  int nb = (N + 255) / 256;
  int ntiles = (N + NT*(BM-1) + BM-1) / BM;

  hipLaunchKernelGGL(k_init,     dim3(1),   dim3(64),  0, stream, ws);
  hipLaunchKernelGGL(k_detect,   dim3(1),   dim3(256), 0, stream, typ, ws);
  hipLaunchKernelGGL(k_count,    dim3(nb),  dim3(256), 0, stream, typ, ws, N);
  hipLaunchKernelGGL(k_scan,     dim3(1),   dim3(1),   0, stream, ws);
  hipLaunchKernelGGL(k_scatter,  dim3(nb),  dim3(256), 0, stream, typ, ws, N);
  hipLaunchKernelGGL(k_tiletype, dim3((ntiles+255)/256), dim3(256), 0, stream, ws, ntiles);
  hipLaunchKernelGGL(k_prep_uf,  dim3((NT*128*16+255)/256), dim3(256), 0, stream, U_f, wsc);
  hipLaunchKernelGGL(k_prep_w,   dim3((NT*384*32+255)/256), dim3(256), 0, stream, W_iou, U_iou, wsc);
  hipLaunchKernelGGL(k_fused,    dim3(ntiles), dim3(256), 0, stream,
                     x, n_h, n_c, b_iou, b_f, wsc, out, N);
}